// Round 16
// baseline (105.497 us; speedup 1.0000x reference)
//
#include <hip/hip_runtime.h>

#define B_SZ   2
#define NH     16
#define S_LEN  2048
#define DK     64
#define EMB    1024
#define M_TOT  (B_SZ * S_LEN)   // 4096
#define KT     64

typedef float          f32x4  __attribute__((ext_vector_type(4)));
typedef float          f32x16 __attribute__((ext_vector_type(16)));
typedef unsigned int   u32x4  __attribute__((ext_vector_type(4)));
typedef unsigned short u16x8  __attribute__((ext_vector_type(8)));
typedef unsigned short u16x4  __attribute__((ext_vector_type(4)));
typedef __bf16         bf16x8 __attribute__((ext_vector_type(8)));

static __device__ __forceinline__ f32x4 mfma16(u16x8 a, u16x8 b, f32x4 c) {
    return __builtin_amdgcn_mfma_f32_16x16x32_bf16(
        __builtin_bit_cast(bf16x8, a), __builtin_bit_cast(bf16x8, b), c, 0, 0, 0);
}
static __device__ __forceinline__ f32x16 mfma32(u16x8 a, u16x8 b, f32x16 c) {
    return __builtin_amdgcn_mfma_f32_32x32x16_bf16(
        __builtin_bit_cast(bf16x8, a), __builtin_bit_cast(bf16x8, b), c, 0, 0, 0);
}

// round-to-nearest-even fp32 -> bf16 (finite inputs)
static __device__ __forceinline__ unsigned short f2bf(float f) {
    unsigned int u = __builtin_bit_cast(unsigned int, f);
    u = (u + 0x7FFFu + ((u >> 16) & 1u)) >> 16;
    return (unsigned short)u;
}

// hardware 2^x
static __device__ __forceinline__ float exp2_hw(float x) {
    float r; asm("v_exp_f32 %0, %1" : "=v"(r) : "v"(x)); return r;
}

// raw barrier with compiler memory fence (no implicit vmcnt drain)
static __device__ __forceinline__ void barrier_raw() {
    asm volatile("s_barrier" ::: "memory");
}
#define VMCNT4() asm volatile("s_waitcnt vmcnt(4)" ::: "memory")
#define VMCNT0() asm volatile("s_waitcnt vmcnt(0)" ::: "memory")

// async global -> LDS, 16B per lane; LDS dest = uniform base + lane*16
#define GLDS16(g, l)  __builtin_amdgcn_global_load_lds(                      \
    (const void __attribute__((address_space(1)))*)(g),                      \
    (void __attribute__((address_space(3)))*)(l), 16, 0, 0)

// ---------------------------------------------------------------- convert
__global__ __launch_bounds__(256) void cvt_kernel(
    const float* __restrict__ x,  const float* __restrict__ wq,
    const float* __restrict__ wk, const float* __restrict__ wv,
    unsigned short* __restrict__ xb,  unsigned short* __restrict__ wqb,
    unsigned short* __restrict__ wkb, unsigned short* __restrict__ wvb)
{
    long gid = (long)blockIdx.x * 256 + threadIdx.x;
    long e = gid * 4;
    const float* src; unsigned short* dst; long off;
    if      (e < 4194304L) { src = x;  dst = xb;  off = e; }
    else if (e < 5242880L) { src = wq; dst = wqb; off = e - 4194304L; }
    else if (e < 6291456L) { src = wk; dst = wkb; off = e - 5242880L; }
    else                   { src = wv; dst = wvb; off = e - 6291456L; }
    f32x4 v = *(const f32x4*)(src + off);
    u16x4 u;
    u[0] = f2bf(v[0]); u[1] = f2bf(v[1]); u[2] = f2bf(v[2]); u[3] = f2bf(v[3]);
    *(u16x4*)(dst + off) = u;
}

// ---------------------------------------------------------------- QKV GEMM
// Fused GEMM C[4096][3072] = xb * Wfused^T.  128x128 tiles -> 24x32 = 768
// blocks = EXACTLY 3/CU (was 192 = 0.75/CU).  BK=32, 3-deep LDS ring
// (48 KB -> 3 blocks/CU fit), ONE barrier per K-step, counted vmcnt(4).
// Both-sides XOR swizzle; XCD-aware swizzle (768%8==0, 96 ids/XCD,
// y-inner -> each B-panel reused 32x from XCD-private L2).
__global__ __launch_bounds__(256) void qkv_gemm(
    const unsigned short* __restrict__ xb,
    const unsigned short* __restrict__ wb,   // fused [3072][1024] bf16
    const float* __restrict__ bq, const float* __restrict__ bk,
    const float* __restrict__ bv,
    unsigned short* __restrict__ qkv)
{
    const int tid  = threadIdx.x;
    const int lane = tid & 63;
    const int wid  = tid >> 6;                  // 0..3
    const int wm   = wid >> 1, wn = wid & 1;    // 2 M-waves x 2 N-waves
    const int lid  = blockIdx.y * 24 + blockIdx.x;   // 0..767
    const int nid  = (lid & 7) * 96 + (lid >> 3);    // XCD-major, bijective
    const int n0   = (nid >> 5) * 128;          // 0..23 n-tiles
    const int m0   = (nid & 31) * 128;          // 0..31 m-tiles
    const int l15  = lane & 15;
    const int k4   = lane >> 4;

    __shared__ __align__(16) unsigned short Al[3][128 * 32];  // 24 KB
    __shared__ __align__(16) unsigned short Bl[3][128 * 32];  // 24 KB

    f32x4 acc[4][4];
#pragma unroll
    for (int i = 0; i < 4; ++i)
#pragma unroll
        for (int j = 0; j < 4; ++j)
            acc[i][j] = (f32x4){0.f, 0.f, 0.f, 0.f};

    // staging: 2 A-loads + 2 B-loads per thread per K-tile.
    // lin = j*256 + tid -> row = lin>>2 (j=0: 0..63, j=1: 64..127),
    // slot = tid&3; source col pre-swizzled (slot ^ (row&3))*8.
    const int row0 = tid >> 2, row1 = 64 + row0;
    const int sl   = tid & 3;
    const int c0   = (sl ^ (row0 & 3)) << 3;
    const int c1   = (sl ^ (row1 & 3)) << 3;
    const int d0   = (wid * 64) * 8;            // LDS elem offset, j=0
    const int d1   = (256 + wid * 64) * 8;      // j=1
    const unsigned short* gA0 = xb + (size_t)(m0 + row0) * EMB + c0;
    const unsigned short* gA1 = xb + (size_t)(m0 + row1) * EMB + c1;
    const unsigned short* gB0 = wb + (size_t)(n0 + row0) * EMB + c0;
    const unsigned short* gB1 = wb + (size_t)(n0 + row1) * EMB + c1;

#define STAGE(kt, b) do {                                       \
        GLDS16(gA0 + (kt) * 32, &Al[b][d0]);                    \
        GLDS16(gA1 + (kt) * 32, &Al[b][d1]);                    \
        GLDS16(gB0 + (kt) * 32, &Bl[b][d0]);                    \
        GLDS16(gB1 + (kt) * 32, &Bl[b][d1]); } while (0)

    // fragment-read slot (row&3 == l15&3 for all fragment rows)
    const int rsl = (k4 ^ (l15 & 3)) << 3;
    const int abase = wm * 64 + l15;            // + i*16
    const int bbase = wn * 64 + l15;            // + j*16

    // prologue: stage K-tiles 0,1 into bufs 0,1 (8 loads outstanding)
    STAGE(0, 0);
    STAGE(1, 1);
    VMCNT4();          // kt0's 4 loads landed
    barrier_raw();

    int bufsel = 0;    // kt % 3, tracked incrementally
    for (int kt = 0; kt < 32; ++kt) {
        const unsigned short* Ab = Al[bufsel];
        const unsigned short* Bb = Bl[bufsel];

        u16x8 a[4], b4[4];
#pragma unroll
        for (int i = 0; i < 4; ++i)
            a[i] = *(const u16x8*)&Ab[(abase + i * 16) * 32 + rsl];
#pragma unroll
        for (int j = 0; j < 4; ++j)
            b4[j] = *(const u16x8*)&Bb[(bbase + j * 16) * 32 + rsl];

        // prefetch kt+2 into the buffer last read at iter kt-1 (idle now)
        int nb3 = bufsel + 2; if (nb3 >= 3) nb3 -= 3;
        if (kt + 2 < 32) STAGE(kt + 2, nb3);

        __builtin_amdgcn_s_setprio(1);
#pragma unroll
        for (int i = 0; i < 4; ++i)
#pragma unroll
            for (int j = 0; j < 4; ++j)
                acc[i][j] = mfma16(a[i], b4[j], acc[i][j]);
        __builtin_amdgcn_s_setprio(0);

        // counted checkpoint: kt+1's buffer must be landed after barrier.
        // steady state: outstanding = 4 (kt+1... already waited) + new 8?
        // accounting: after STAGE(kt+2): outstanding <= 8 (kt+1, kt+2).
        if (kt == 30) VMCNT0(); else VMCNT4();
        barrier_raw();

        bufsel += 1; if (bufsel >= 3) bufsel -= 3;
    }

    // epilogue: bias + bf16 store to [B,H,S,D] of matrix mat
    const int mat = n0 >> 10;                    // block-uniform
    const float* bias = (mat == 0) ? bq : ((mat == 1) ? bk : bv);
    unsigned short* dst = qkv + (size_t)mat * ((size_t)M_TOT * EMB);
    const int nb = (n0 & 1023) + wn * 64;
#pragma unroll
    for (int fc = 0; fc < 4; ++fc) {
        const int nl = nb + fc * 16 + l15;       // 0..1023 within matrix
        const float bvv = bias[nl];
        const int h = nl >> 6, d = nl & 63;
#pragma unroll
        for (int fr = 0; fr < 4; ++fr) {
#pragma unroll
            for (int rr = 0; rr < 4; ++rr) {
                const int m = m0 + wm * 64 + fr * 16 + k4 * 4 + rr;
                const int bb = m >> 11, s = m & 2047;
                dst[((size_t)((bb * NH + h) * S_LEN + s)) * DK + d] =
                    f2bf(acc[fr][fc][rr] + bvv);
            }
        }
    }
#undef STAGE
}

// ---------------------------------------------------------------- attention
// Round-15 structure + MFMA CHAIN-DEPTH SPLIT: QK accumulators st0/st1 and
// PV accumulators o0/o1 split into a/b halves (ks 0-1 vs 2-3) -> dependent
// chains go 4-deep -> 2-deep, ILP 2->4 (QK) and 3->5 (PV).  Targets the
// ~5K-cycle/iter latency gap the occupancy experiments (r13-r15) isolated.
__global__ __launch_bounds__(512) void attn_kernel(
    const unsigned short* __restrict__ Q,
    const unsigned short* __restrict__ K,
    const unsigned short* __restrict__ V,
    const int* __restrict__ mskp,
    float* __restrict__ out)
{
    const int tid = threadIdx.x, lane = tid & 63, wid = tid >> 6;
    const int grp = wid >> 2, qw = wid & 3;
    const int l31 = lane & 31, H = lane >> 5;
    const int bh = blockIdx.x;
    const int h  = bh & 15, b = bh >> 4;
    const int yp = blockIdx.y;             // 0..7: serial pair (yp, 15-yp)
    const size_t hoff = ((size_t)(b * NH + h)) * S_LEN * DK;
    const unsigned short* Qh = Q + hoff;
    const unsigned short* Kh = K + hoff;
    const unsigned short* Vh = V + hoff;
    const int msk = *mskp;

    __shared__ __align__(16) unsigned short Kl[2][2][64 * 64];  // [grp][buf]
    __shared__ __align__(16) unsigned short Vt[2][2][64 * 64];
    __shared__ float MLbuf[512];

    u16x8 ones1;
#pragma unroll
    for (int i = 0; i < 8; ++i) ones1[i] = 0x3F80;   // bf16 1.0

    const int gt  = tid & 255;              // thread within group
    const int sr0 = gt >> 3, sc8 = gt & 7, sr1 = sr0 + 32;
    const int kwo0 = sr0 * 64 + ((sc8 ^ (sr0 & 7)) << 3);
    const int kwo1 = sr1 * 64 + ((sc8 ^ (sr1 & 7)) << 3);
    const int vwo0 = (((sr0 >> 3) ^ sc8) << 3) + (sr0 & 7);
    const int vwo1 = (((sr1 >> 3) ^ sc8) << 3) + (sr1 & 7);

    const int dsw0 = l31 >> 3, dsw1 = 4 + (l31 >> 3);
    const int rsw  = l31 & 7;
    const float SC2 = 0.125f * 1.4426950408889634f;   // fold log2(e)
    const int idx  = qw * 64 + lane;                  // merge row index

    for (int seg = 0; seg < 2; ++seg) {
        const int qt = seg ? (15 - yp) : yp;
        const int q0 = qt * 128;
        const int ntiles = msk ? (2 * qt + 2) : (S_LEN / KT);  // even
        const int niter  = ntiles >> 1;
        const int qrow = q0 + qw * 32 + l31;
        const int qmin = q0 + qw * 32;

        u16x8 qf[4];
#pragma unroll
        for (int ks = 0; ks < 4; ++ks)
            qf[ks] = *(const u16x8*)(Qh + (size_t)qrow * DK + ks * 16 + H * 8);

        f32x16 o0a, o0b, o1a, o1b, lacc;
#pragma unroll
        for (int i = 0; i < 16; ++i) {
            o0a[i] = 0.f; o0b[i] = 0.f; o1a[i] = 0.f; o1b[i] = 0.f;
            lacc[i] = 0.f;
        }
        float mx = -1e30f;

        // ---- prologue: load tile 'grp' to regs; stage buf0; prefetch ----
        u16x8 kr[2], vr[2];
        {
            const unsigned short* K0 = Kh + (size_t)grp * KT * DK;
            const unsigned short* V0 = Vh + (size_t)grp * KT * DK;
            kr[0] = *(const u16x8*)(K0 + (size_t)sr0 * DK + sc8 * 8);
            vr[0] = *(const u16x8*)(V0 + (size_t)sr0 * DK + sc8 * 8);
            kr[1] = *(const u16x8*)(K0 + (size_t)sr1 * DK + sc8 * 8);
            vr[1] = *(const u16x8*)(V0 + (size_t)sr1 * DK + sc8 * 8);
        }
        __syncthreads();   // (seg=1) previous merge's LDS reads done
        {
            unsigned short* Kg = Kl[grp][0];
            unsigned short* Vg = Vt[grp][0];
            *(u16x8*)&Kg[kwo0] = kr[0];
            *(u16x8*)&Kg[kwo1] = kr[1];
#pragma unroll
            for (int e = 0; e < 8; ++e) {
                Vg[(sc8 * 8 + e) * 64 + vwo0] = vr[0][e];
                Vg[(sc8 * 8 + e) * 64 + vwo1] = vr[1][e];
            }
            if (grp + 2 < ntiles) {
                const unsigned short* Kn = Kh + (size_t)(grp + 2) * KT * DK;
                const unsigned short* Vn = Vh + (size_t)(grp + 2) * KT * DK;
                kr[0] = *(const u16x8*)(Kn + (size_t)sr0 * DK + sc8 * 8);
                vr[0] = *(const u16x8*)(Vn + (size_t)sr0 * DK + sc8 * 8);
                kr[1] = *(const u16x8*)(Kn + (size_t)sr1 * DK + sc8 * 8);
                vr[1] = *(const u16x8*)(Vn + (size_t)sr1 * DK + sc8 * 8);
            }
        }
        __syncthreads();

        int cur = 0;
        for (int it = 0; it < niter; ++it) {
            const int kt = 2 * it + grp;

            // ---- write NEXT tile (kt+2) into buf^1; overlaps compute ----
            if (kt + 2 < ntiles) {
                unsigned short* Kg = Kl[grp][cur ^ 1];
                unsigned short* Vg = Vt[grp][cur ^ 1];
                *(u16x8*)&Kg[kwo0] = kr[0];
                *(u16x8*)&Kg[kwo1] = kr[1];
#pragma unroll
                for (int e = 0; e < 8; ++e) {
                    Vg[(sc8 * 8 + e) * 64 + vwo0] = vr[0][e];
                    Vg[(sc8 * 8 + e) * 64 + vwo1] = vr[1][e];
                }
            }
            // ---- prefetch tile kt+4 into regs ----
            if (kt + 4 < ntiles) {
                const unsigned short* Kn = Kh + (size_t)(kt + 4) * KT * DK;
                const unsigned short* Vn = Vh + (size_t)(kt + 4) * KT * DK;
                kr[0] = *(const u16x8*)(Kn + (size_t)sr0 * DK + sc8 * 8);
                vr[0] = *(const u16x8*)(Vn + (size_t)sr0 * DK + sc8 * 8);
                kr[1] = *(const u16x8*)(Kn + (size_t)sr1 * DK + sc8 * 8);
                vr[1] = *(const u16x8*)(Vn + (size_t)sr1 * DK + sc8 * 8);
            }

            // ---- compute tile kt from buf[cur] (skip if fully masked) ----
            if (!(msk && kt * KT > qmin + 31)) {
                const unsigned short* Kg = Kl[grp][cur];
                const unsigned short* Vg = Vt[grp][cur];

                // S^T = K Q^T : split accumulators, 2-deep chains, ILP 4
                f32x16 st0a, st0b, st1a, st1b;
#pragma unroll
                for (int i = 0; i < 16; ++i) {
                    st0a[i] = 0.f; st0b[i] = 0.f; st1a[i] = 0.f; st1b[i] = 0.f;
                }
#pragma unroll
                for (int ks = 0; ks < 2; ++ks) {
                    const int g = (((ks << 1) + H) ^ rsw) << 3;
                    u16x8 kf0 = *(const u16x8*)&Kg[l31 * 64 + g];
                    u16x8 kf1 = *(const u16x8*)&Kg[(32 + l31) * 64 + g];
                    st0a = mfma32(kf0, qf[ks], st0a);
                    st1a = mfma32(kf1, qf[ks], st1a);
                }
#pragma unroll
                for (int ks = 2; ks < 4; ++ks) {
                    const int g = (((ks << 1) + H) ^ rsw) << 3;
                    u16x8 kf0 = *(const u16x8*)&Kg[l31 * 64 + g];
                    u16x8 kf1 = *(const u16x8*)&Kg[(32 + l31) * 64 + g];
                    st0b = mfma32(kf0, qf[ks], st0b);
                    st1b = mfma32(kf1, qf[ks], st1b);
                }
                f32x16 st0 = (st0a + st0b) * SC2;
                f32x16 st1 = (st1a + st1b) * SC2;

                float p[32];
#pragma unroll
                for (int r = 0; r < 16; ++r) { p[r] = st0[r]; p[16 + r] = st1[r]; }
                const bool needmask = msk && (kt * KT + 63 > qrow);
                if (needmask) {
#pragma unroll
                    for (int r = 0; r < 16; ++r) {
                        const int krow = (r & 3) + 8 * (r >> 2) + 4 * H;
                        if (kt * KT + krow > qrow)      p[r]      = -1e30f;
                        if (kt * KT + 32 + krow > qrow) p[16 + r] = -1e30f;
                    }
                }

                // tile max: register tree + one shfl(32); defer-max rescale
                float t8[8];
#pragma unroll
                for (int i = 0; i < 8; ++i)
                    t8[i] = fmaxf(fmaxf(p[i], p[i + 8]), fmaxf(p[i + 16], p[i + 24]));
#pragma unroll
                for (int i = 0; i < 4; ++i) t8[i] = fmaxf(t8[i], t8[i + 4]);
                float mt = fmaxf(fmaxf(t8[0], t8[1]), fmaxf(t8[2], t8[3]));
                mt = fmaxf(mt, __shfl_xor(mt, 32, 64));

                if (!__all(mt <= mx + 11.54f)) {   // 8 nats in log2 domain
                    const float mn = fmaxf(mx, mt);
                    const float al = exp2_hw(mx - mn);
                    mx = mn;
                    o0a *= al; o0b *= al; o1a *= al; o1b *= al;
                    lacc[0] *= al;
                }

#pragma unroll
                for (int r = 0; r < 32; ++r) p[r] = exp2_hw(p[r] - mx);

                // P^T -> bf16 B-fragments; PV with split accumulators
#pragma unroll
                for (int ks = 0; ks < 4; ++ks) {
                    const int bb = ks * 8;
                    unsigned int wa, wb2, wc, wd;
                    asm("v_cvt_pk_bf16_f32 %0, %1, %2" : "=v"(wa)  : "v"(p[bb + 0]), "v"(p[bb + 1]));
                    asm("v_cvt_pk_bf16_f32 %0, %1, %2" : "=v"(wb2) : "v"(p[bb + 2]), "v"(p[bb + 3]));
                    asm("v_cvt_pk_bf16_f32 %0, %1, %2" : "=v"(wc)  : "v"(p[bb + 4]), "v"(p[bb + 5]));
                    asm("v_cvt_pk_bf16_f32 %0, %1, %2" : "=v"(wd)  : "v"(p[bb + 6]), "v"(p[bb + 7]));
                    asm volatile("v_permlane32_swap_b32 %0, %1" : "+v"(wa),  "+v"(wc));
                    asm volatile("v_permlane32_swap_b32 %0, %1" : "+v"(wb2), "+v"(wd));
                    u32x4 wv; wv[0] = wa; wv[1] = wb2; wv[2] = wc; wv[3] = wd;
                    const u16x8 pb = __builtin_bit_cast(u16x8, wv);
                    const int kg = (ks << 1) + H;
                    u16x8 vf0 = *(const u16x8*)&Vg[l31 * 64        + ((kg ^ dsw0) << 3)];
                    u16x8 vf1 = *(const u16x8*)&Vg[(32 + l31) * 64 + ((kg ^ dsw1) << 3)];
                    if (ks < 2) {
                        o0a = mfma32(vf0, pb, o0a);
                        o1a = mfma32(vf1, pb, o1a);
                    } else {
                        o0b = mfma32(vf0, pb, o0b);
                        o1b = mfma32(vf1, pb, o1b);
                    }
                    lacc = mfma32(ones1, pb, lacc);
                }
            }

            __syncthreads();   // buf^1 writes visible; buf readers done
            cur ^= 1;
        }

        // combine split accumulators
        const f32x16 o0 = o0a + o0b;
        const f32x16 o1 = o1a + o1b;

        // ---- merge group 0 + group 1 (LSE combine) ----
        // MO: 256 rows x 32 floats = 32 KB = exactly sizeof(Kl).
        float* MO = (float*)Kl + idx * 32;
        const float lsum = lacc[0];
        if (grp == 1) {
#pragma unroll
            for (int i = 0; i < 16; ++i) {
                MO[(i + idx) & 31]      = o0[i];
                MO[(16 + i + idx) & 31] = o1[i];
            }
            MLbuf[idx * 2]     = mx;
            MLbuf[idx * 2 + 1] = lsum;
        }
        __syncthreads();
        if (grp == 0) {
            const float m2 = MLbuf[idx * 2], l2 = MLbuf[idx * 2 + 1];
            const float mn = fmaxf(mx, m2);
            const float ea = exp2_hw(mx - mn);
            const float eb = exp2_hw(m2 - mn);
            const float inv = 1.f / (lsum * ea + l2 * eb);
            float* orow = out + ((size_t)(b * S_LEN) + qrow) * EMB + h * DK;
#pragma unroll
            for (int g = 0; g < 4; ++g) {
                f32x4 w0, w1;
#pragma unroll
                for (int i = 0; i < 4; ++i) {
                    w0[i] = (o0[4 * g + i] * ea + MO[(4 * g + i + idx) & 31] * eb) * inv;
                    w1[i] = (o1[4 * g + i] * ea + MO[(16 + 4 * g + i + idx) & 31] * eb) * inv;
                }
                *(f32x4*)&orow[8 * g + 4 * H]      = w0;
                *(f32x4*)&orow[32 + 8 * g + 4 * H] = w1;
            }
        }
        // next seg's prologue __syncthreads guards MO reads vs restaging
    }
}

// ---------------------------------------------------------------- launch
extern "C" void kernel_launch(void* const* d_in, const int* in_sizes, int n_in,
                              void* d_out, int out_size, void* d_ws, size_t ws_size,
                              hipStream_t stream)
{
    const float* x  = (const float*)d_in[0];
    const float* wq = (const float*)d_in[1];
    const float* bq = (const float*)d_in[2];
    const float* wk = (const float*)d_in[3];
    const float* bk = (const float*)d_in[4];
    const float* wv = (const float*)d_in[5];
    const float* bv = (const float*)d_in[6];
    const int* msk  = (const int*)d_in[7];
    float* out = (float*)d_out;

    unsigned short* xb  = (unsigned short*)d_ws;
    unsigned short* wb  = xb + (size_t)M_TOT * EMB;   // fused [3072][1024]
    unsigned short* qkv = wb + (size_t)3 * 1024 * 1024;

    cvt_kernel<<<7168, 256, 0, stream>>>(x, wq, wk, wv,
                                         xb, wb, wb + 1024 * 1024, wb + 2 * 1024 * 1024);
    qkv_gemm<<<dim3(24, 32, 1), 256, 0, stream>>>(xb, wb, bq, bk, bv, qkv);
    attn_kernel<<<dim3(32, 8, 1), 512, 0, stream>>>(
        qkv, qkv + (size_t)M_TOT * EMB, qkv + (size_t)2 * M_TOT * EMB, msk, out);
}

// Round 17
// 84.627 us; speedup vs baseline: 1.2466x; 1.2466x over previous
//
#include <hip/hip_runtime.h>

#define B_SZ   2
#define NH     16
#define S_LEN  2048
#define DK     64
#define EMB    1024
#define M_TOT  (B_SZ * S_LEN)   // 4096
#define KT     64

typedef float          f32x4  __attribute__((ext_vector_type(4)));
typedef float          f32x16 __attribute__((ext_vector_type(16)));
typedef unsigned int   u32x4  __attribute__((ext_vector_type(4)));
typedef unsigned short u16x8  __attribute__((ext_vector_type(8)));
typedef unsigned short u16x4  __attribute__((ext_vector_type(4)));
typedef __bf16         bf16x8 __attribute__((ext_vector_type(8)));

static __device__ __forceinline__ f32x4 mfma16(u16x8 a, u16x8 b, f32x4 c) {
    return __builtin_amdgcn_mfma_f32_16x16x32_bf16(
        __builtin_bit_cast(bf16x8, a), __builtin_bit_cast(bf16x8, b), c, 0, 0, 0);
}
static __device__ __forceinline__ f32x16 mfma32(u16x8 a, u16x8 b, f32x16 c) {
    return __builtin_amdgcn_mfma_f32_32x32x16_bf16(
        __builtin_bit_cast(bf16x8, a), __builtin_bit_cast(bf16x8, b), c, 0, 0, 0);
}

// round-to-nearest-even fp32 -> bf16 (finite inputs)
static __device__ __forceinline__ unsigned short f2bf(float f) {
    unsigned int u = __builtin_bit_cast(unsigned int, f);
    u = (u + 0x7FFFu + ((u >> 16) & 1u)) >> 16;
    return (unsigned short)u;
}

// hardware 2^x
static __device__ __forceinline__ float exp2_hw(float x) {
    float r; asm("v_exp_f32 %0, %1" : "=v"(r) : "v"(x)); return r;
}

// raw barrier with compiler memory fence (no implicit vmcnt drain)
static __device__ __forceinline__ void barrier_raw() {
    asm volatile("s_barrier" ::: "memory");
}
#define VMCNT4() asm volatile("s_waitcnt vmcnt(4)" ::: "memory")
#define VMCNT0() asm volatile("s_waitcnt vmcnt(0)" ::: "memory")

// async global -> LDS, 16B per lane; LDS dest = uniform base + lane*16
#define GLDS16(g, l)  __builtin_amdgcn_global_load_lds(                      \
    (const void __attribute__((address_space(1)))*)(g),                      \
    (void __attribute__((address_space(3)))*)(l), 16, 0, 0)

// ---------------------------------------------------------------- convert
__global__ __launch_bounds__(256) void cvt_kernel(
    const float* __restrict__ x,  const float* __restrict__ wq,
    const float* __restrict__ wk, const float* __restrict__ wv,
    unsigned short* __restrict__ xb,  unsigned short* __restrict__ wqb,
    unsigned short* __restrict__ wkb, unsigned short* __restrict__ wvb)
{
    long gid = (long)blockIdx.x * 256 + threadIdx.x;
    long e = gid * 4;
    const float* src; unsigned short* dst; long off;
    if      (e < 4194304L) { src = x;  dst = xb;  off = e; }
    else if (e < 5242880L) { src = wq; dst = wqb; off = e - 4194304L; }
    else if (e < 6291456L) { src = wk; dst = wkb; off = e - 5242880L; }
    else                   { src = wv; dst = wvb; off = e - 6291456L; }
    f32x4 v = *(const f32x4*)(src + off);
    u16x4 u;
    u[0] = f2bf(v[0]); u[1] = f2bf(v[1]); u[2] = f2bf(v[2]); u[3] = f2bf(v[3]);
    *(u16x4*)(dst + off) = u;
}

// ---------------------------------------------------------------- QKV GEMM
// Fused GEMM C[4096][3072] = xb * Wfused^T.  128x128 tiles -> 24x32 = 768
// blocks = EXACTLY 3/CU.  BK=32, 3-deep LDS ring (48 KB), ONE barrier per
// K-step, counted vmcnt(4).  Both-sides XOR swizzle; XCD-aware swizzle.
// (round-16 proven: gemm ~29 us vs 35.6 for the 256^2 variant)
__global__ __launch_bounds__(256) void qkv_gemm(
    const unsigned short* __restrict__ xb,
    const unsigned short* __restrict__ wb,   // fused [3072][1024] bf16
    const float* __restrict__ bq, const float* __restrict__ bk,
    const float* __restrict__ bv,
    unsigned short* __restrict__ qkv)
{
    const int tid  = threadIdx.x;
    const int lane = tid & 63;
    const int wid  = tid >> 6;                  // 0..3
    const int wm   = wid >> 1, wn = wid & 1;    // 2 M-waves x 2 N-waves
    const int lid  = blockIdx.y * 24 + blockIdx.x;   // 0..767
    const int nid  = (lid & 7) * 96 + (lid >> 3);    // XCD-major, bijective
    const int n0   = (nid >> 5) * 128;          // 0..23 n-tiles
    const int m0   = (nid & 31) * 128;          // 0..31 m-tiles
    const int l15  = lane & 15;
    const int k4   = lane >> 4;

    __shared__ __align__(16) unsigned short Al[3][128 * 32];  // 24 KB
    __shared__ __align__(16) unsigned short Bl[3][128 * 32];  // 24 KB

    f32x4 acc[4][4];
#pragma unroll
    for (int i = 0; i < 4; ++i)
#pragma unroll
        for (int j = 0; j < 4; ++j)
            acc[i][j] = (f32x4){0.f, 0.f, 0.f, 0.f};

    const int row0 = tid >> 2, row1 = 64 + row0;
    const int sl   = tid & 3;
    const int c0   = (sl ^ (row0 & 3)) << 3;
    const int c1   = (sl ^ (row1 & 3)) << 3;
    const int d0   = (wid * 64) * 8;            // LDS elem offset, j=0
    const int d1   = (256 + wid * 64) * 8;      // j=1
    const unsigned short* gA0 = xb + (size_t)(m0 + row0) * EMB + c0;
    const unsigned short* gA1 = xb + (size_t)(m0 + row1) * EMB + c1;
    const unsigned short* gB0 = wb + (size_t)(n0 + row0) * EMB + c0;
    const unsigned short* gB1 = wb + (size_t)(n0 + row1) * EMB + c1;

#define STAGE(kt, b) do {                                       \
        GLDS16(gA0 + (kt) * 32, &Al[b][d0]);                    \
        GLDS16(gA1 + (kt) * 32, &Al[b][d1]);                    \
        GLDS16(gB0 + (kt) * 32, &Bl[b][d0]);                    \
        GLDS16(gB1 + (kt) * 32, &Bl[b][d1]); } while (0)

    const int rsl = (k4 ^ (l15 & 3)) << 3;
    const int abase = wm * 64 + l15;            // + i*16
    const int bbase = wn * 64 + l15;            // + j*16

    STAGE(0, 0);
    STAGE(1, 1);
    VMCNT4();          // kt0's 4 loads landed
    barrier_raw();

    int bufsel = 0;    // kt % 3, tracked incrementally
    for (int kt = 0; kt < 32; ++kt) {
        const unsigned short* Ab = Al[bufsel];
        const unsigned short* Bb = Bl[bufsel];

        u16x8 a[4], b4[4];
#pragma unroll
        for (int i = 0; i < 4; ++i)
            a[i] = *(const u16x8*)&Ab[(abase + i * 16) * 32 + rsl];
#pragma unroll
        for (int j = 0; j < 4; ++j)
            b4[j] = *(const u16x8*)&Bb[(bbase + j * 16) * 32 + rsl];

        // prefetch kt+2 into the buffer last read at iter kt-1 (idle now)
        int nb3 = bufsel + 2; if (nb3 >= 3) nb3 -= 3;
        if (kt + 2 < 32) STAGE(kt + 2, nb3);

        __builtin_amdgcn_s_setprio(1);
#pragma unroll
        for (int i = 0; i < 4; ++i)
#pragma unroll
            for (int j = 0; j < 4; ++j)
                acc[i][j] = mfma16(a[i], b4[j], acc[i][j]);
        __builtin_amdgcn_s_setprio(0);

        if (kt == 30) VMCNT0(); else VMCNT4();
        barrier_raw();

        bufsel += 1; if (bufsel >= 3) bufsel -= 3;
    }

    const int mat = n0 >> 10;                    // block-uniform
    const float* bias = (mat == 0) ? bq : ((mat == 1) ? bk : bv);
    unsigned short* dst = qkv + (size_t)mat * ((size_t)M_TOT * EMB);
    const int nb = (n0 & 1023) + wn * 64;
#pragma unroll
    for (int fc = 0; fc < 4; ++fc) {
        const int nl = nb + fc * 16 + l15;       // 0..1023 within matrix
        const float bvv = bias[nl];
        const int h = nl >> 6, d = nl & 63;
#pragma unroll
        for (int fr = 0; fr < 4; ++fr) {
#pragma unroll
            for (int rr = 0; rr < 4; ++rr) {
                const int m = m0 + wm * 64 + fr * 16 + k4 * 4 + rr;
                const int bb = m >> 11, s = m & 2047;
                dst[((size_t)((bb * NH + h) * S_LEN + s)) * DK + d] =
                    f2bf(acc[fr][fc][rr] + bvv);
            }
        }
    }
#undef STAGE
}

// ---------------------------------------------------------------- attention
// EXACT round-15 kernel (43.4 us): serial q-tile pairing, double-buffered,
// swapped QK^T, exp2 softmax, defer-max, lsum ones-MFMA, cvt_pk+permlane32,
// no setprio.  Round-16's split-accumulator variant spilled (+48 VGPR past
// the 128 bin -> FETCH doubled) and is reverted.
__global__ __launch_bounds__(512) void attn_kernel(
    const unsigned short* __restrict__ Q,
    const unsigned short* __restrict__ K,
    const unsigned short* __restrict__ V,
    const int* __restrict__ mskp,
    float* __restrict__ out)
{
    const int tid = threadIdx.x, lane = tid & 63, wid = tid >> 6;
    const int grp = wid >> 2, qw = wid & 3;
    const int l31 = lane & 31, H = lane >> 5;
    const int bh = blockIdx.x;
    const int h  = bh & 15, b = bh >> 4;
    const int yp = blockIdx.y;             // 0..7: serial pair (yp, 15-yp)
    const size_t hoff = ((size_t)(b * NH + h)) * S_LEN * DK;
    const unsigned short* Qh = Q + hoff;
    const unsigned short* Kh = K + hoff;
    const unsigned short* Vh = V + hoff;
    const int msk = *mskp;

    __shared__ __align__(16) unsigned short Kl[2][2][64 * 64];  // [grp][buf]
    __shared__ __align__(16) unsigned short Vt[2][2][64 * 64];
    __shared__ float MLbuf[512];

    u16x8 ones1;
#pragma unroll
    for (int i = 0; i < 8; ++i) ones1[i] = 0x3F80;   // bf16 1.0

    const int gt  = tid & 255;              // thread within group
    const int sr0 = gt >> 3, sc8 = gt & 7, sr1 = sr0 + 32;
    const int kwo0 = sr0 * 64 + ((sc8 ^ (sr0 & 7)) << 3);
    const int kwo1 = sr1 * 64 + ((sc8 ^ (sr1 & 7)) << 3);
    const int vwo0 = (((sr0 >> 3) ^ sc8) << 3) + (sr0 & 7);
    const int vwo1 = (((sr1 >> 3) ^ sc8) << 3) + (sr1 & 7);

    const int dsw0 = l31 >> 3, dsw1 = 4 + (l31 >> 3);
    const int rsw  = l31 & 7;
    const float SC2 = 0.125f * 1.4426950408889634f;   // fold log2(e)
    const int idx  = qw * 64 + lane;                  // merge row index

    for (int seg = 0; seg < 2; ++seg) {
        const int qt = seg ? (15 - yp) : yp;
        const int q0 = qt * 128;
        const int ntiles = msk ? (2 * qt + 2) : (S_LEN / KT);  // even
        const int niter  = ntiles >> 1;
        const int qrow = q0 + qw * 32 + l31;
        const int qmin = q0 + qw * 32;

        u16x8 qf[4];
#pragma unroll
        for (int ks = 0; ks < 4; ++ks)
            qf[ks] = *(const u16x8*)(Qh + (size_t)qrow * DK + ks * 16 + H * 8);

        f32x16 o0, o1, lacc;
#pragma unroll
        for (int i = 0; i < 16; ++i) { o0[i] = 0.f; o1[i] = 0.f; lacc[i] = 0.f; }
        float mx = -1e30f;

        // ---- prologue: load tile 'grp' to regs; stage buf0; prefetch ----
        u16x8 kr[2], vr[2];
        {
            const unsigned short* K0 = Kh + (size_t)grp * KT * DK;
            const unsigned short* V0 = Vh + (size_t)grp * KT * DK;
            kr[0] = *(const u16x8*)(K0 + (size_t)sr0 * DK + sc8 * 8);
            vr[0] = *(const u16x8*)(V0 + (size_t)sr0 * DK + sc8 * 8);
            kr[1] = *(const u16x8*)(K0 + (size_t)sr1 * DK + sc8 * 8);
            vr[1] = *(const u16x8*)(V0 + (size_t)sr1 * DK + sc8 * 8);
        }
        __syncthreads();   // (seg=1) previous merge's LDS reads done
        {
            unsigned short* Kg = Kl[grp][0];
            unsigned short* Vg = Vt[grp][0];
            *(u16x8*)&Kg[kwo0] = kr[0];
            *(u16x8*)&Kg[kwo1] = kr[1];
#pragma unroll
            for (int e = 0; e < 8; ++e) {
                Vg[(sc8 * 8 + e) * 64 + vwo0] = vr[0][e];
                Vg[(sc8 * 8 + e) * 64 + vwo1] = vr[1][e];
            }
            if (grp + 2 < ntiles) {
                const unsigned short* Kn = Kh + (size_t)(grp + 2) * KT * DK;
                const unsigned short* Vn = Vh + (size_t)(grp + 2) * KT * DK;
                kr[0] = *(const u16x8*)(Kn + (size_t)sr0 * DK + sc8 * 8);
                vr[0] = *(const u16x8*)(Vn + (size_t)sr0 * DK + sc8 * 8);
                kr[1] = *(const u16x8*)(Kn + (size_t)sr1 * DK + sc8 * 8);
                vr[1] = *(const u16x8*)(Vn + (size_t)sr1 * DK + sc8 * 8);
            }
        }
        __syncthreads();

        int cur = 0;
        for (int it = 0; it < niter; ++it) {
            const int kt = 2 * it + grp;

            // ---- write NEXT tile (kt+2) into buf^1; overlaps compute ----
            if (kt + 2 < ntiles) {
                unsigned short* Kg = Kl[grp][cur ^ 1];
                unsigned short* Vg = Vt[grp][cur ^ 1];
                *(u16x8*)&Kg[kwo0] = kr[0];
                *(u16x8*)&Kg[kwo1] = kr[1];
#pragma unroll
                for (int e = 0; e < 8; ++e) {
                    Vg[(sc8 * 8 + e) * 64 + vwo0] = vr[0][e];
                    Vg[(sc8 * 8 + e) * 64 + vwo1] = vr[1][e];
                }
            }
            // ---- prefetch tile kt+4 into regs ----
            if (kt + 4 < ntiles) {
                const unsigned short* Kn = Kh + (size_t)(kt + 4) * KT * DK;
                const unsigned short* Vn = Vh + (size_t)(kt + 4) * KT * DK;
                kr[0] = *(const u16x8*)(Kn + (size_t)sr0 * DK + sc8 * 8);
                vr[0] = *(const u16x8*)(Vn + (size_t)sr0 * DK + sc8 * 8);
                kr[1] = *(const u16x8*)(Kn + (size_t)sr1 * DK + sc8 * 8);
                vr[1] = *(const u16x8*)(Vn + (size_t)sr1 * DK + sc8 * 8);
            }

            // ---- compute tile kt from buf[cur] (skip if fully masked) ----
            if (!(msk && kt * KT > qmin + 31)) {
                const unsigned short* Kg = Kl[grp][cur];
                const unsigned short* Vg = Vt[grp][cur];

                // S^T = K Q^T
                f32x16 st0, st1;
#pragma unroll
                for (int i = 0; i < 16; ++i) { st0[i] = 0.f; st1[i] = 0.f; }
#pragma unroll
                for (int ks = 0; ks < 4; ++ks) {
                    const int g = (((ks << 1) + H) ^ rsw) << 3;
                    u16x8 kf0 = *(const u16x8*)&Kg[l31 * 64 + g];
                    u16x8 kf1 = *(const u16x8*)&Kg[(32 + l31) * 64 + g];
                    st0 = mfma32(kf0, qf[ks], st0);
                    st1 = mfma32(kf1, qf[ks], st1);
                }

                // scale (exp2 domain, packed) + causal mask
                st0 *= SC2;
                st1 *= SC2;
                float p[32];
#pragma unroll
                for (int r = 0; r < 16; ++r) { p[r] = st0[r]; p[16 + r] = st1[r]; }
                const bool needmask = msk && (kt * KT + 63 > qrow);
                if (needmask) {
#pragma unroll
                    for (int r = 0; r < 16; ++r) {
                        const int krow = (r & 3) + 8 * (r >> 2) + 4 * H;
                        if (kt * KT + krow > qrow)      p[r]      = -1e30f;
                        if (kt * KT + 32 + krow > qrow) p[16 + r] = -1e30f;
                    }
                }

                // tile max: register tree + one shfl(32); defer-max rescale
                float t8[8];
#pragma unroll
                for (int i = 0; i < 8; ++i)
                    t8[i] = fmaxf(fmaxf(p[i], p[i + 8]), fmaxf(p[i + 16], p[i + 24]));
#pragma unroll
                for (int i = 0; i < 4; ++i) t8[i] = fmaxf(t8[i], t8[i + 4]);
                float mt = fmaxf(fmaxf(t8[0], t8[1]), fmaxf(t8[2], t8[3]));
                mt = fmaxf(mt, __shfl_xor(mt, 32, 64));

                if (!__all(mt <= mx + 11.54f)) {   // 8 nats in log2 domain
                    const float mn = fmaxf(mx, mt);
                    const float al = exp2_hw(mx - mn);
                    mx = mn;
                    o0 *= al; o1 *= al;
                    lacc[0] *= al;
                }

#pragma unroll
                for (int r = 0; r < 32; ++r) p[r] = exp2_hw(p[r] - mx);

                // P^T -> bf16 B-fragments; PV + row-sum via ones-MFMA
#pragma unroll
                for (int ks = 0; ks < 4; ++ks) {
                    const int bb = ks * 8;
                    unsigned int wa, wb2, wc, wd;
                    asm("v_cvt_pk_bf16_f32 %0, %1, %2" : "=v"(wa)  : "v"(p[bb + 0]), "v"(p[bb + 1]));
                    asm("v_cvt_pk_bf16_f32 %0, %1, %2" : "=v"(wb2) : "v"(p[bb + 2]), "v"(p[bb + 3]));
                    asm("v_cvt_pk_bf16_f32 %0, %1, %2" : "=v"(wc)  : "v"(p[bb + 4]), "v"(p[bb + 5]));
                    asm("v_cvt_pk_bf16_f32 %0, %1, %2" : "=v"(wd)  : "v"(p[bb + 6]), "v"(p[bb + 7]));
                    asm volatile("v_permlane32_swap_b32 %0, %1" : "+v"(wa),  "+v"(wc));
                    asm volatile("v_permlane32_swap_b32 %0, %1" : "+v"(wb2), "+v"(wd));
                    u32x4 wv; wv[0] = wa; wv[1] = wb2; wv[2] = wc; wv[3] = wd;
                    const u16x8 pb = __builtin_bit_cast(u16x8, wv);
                    const int kg = (ks << 1) + H;
                    u16x8 vf0 = *(const u16x8*)&Vg[l31 * 64        + ((kg ^ dsw0) << 3)];
                    u16x8 vf1 = *(const u16x8*)&Vg[(32 + l31) * 64 + ((kg ^ dsw1) << 3)];
                    o0 = mfma32(vf0, pb, o0);
                    o1 = mfma32(vf1, pb, o1);
                    lacc = mfma32(ones1, pb, lacc);
                }
            }

            __syncthreads();   // buf^1 writes visible; buf readers done
            cur ^= 1;
        }

        // ---- merge group 0 + group 1 (LSE combine) ----
        // MO: 256 rows x 32 floats = 32 KB = exactly sizeof(Kl).
        float* MO = (float*)Kl + idx * 32;
        const float lsum = lacc[0];
        if (grp == 1) {
#pragma unroll
            for (int i = 0; i < 16; ++i) {
                MO[(i + idx) & 31]      = o0[i];
                MO[(16 + i + idx) & 31] = o1[i];
            }
            MLbuf[idx * 2]     = mx;
            MLbuf[idx * 2 + 1] = lsum;
        }
        __syncthreads();
        if (grp == 0) {
            const float m2 = MLbuf[idx * 2], l2 = MLbuf[idx * 2 + 1];
            const float mn = fmaxf(mx, m2);
            const float ea = exp2_hw(mx - mn);
            const float eb = exp2_hw(m2 - mn);
            const float inv = 1.f / (lsum * ea + l2 * eb);
            float* orow = out + ((size_t)(b * S_LEN) + qrow) * EMB + h * DK;
#pragma unroll
            for (int g = 0; g < 4; ++g) {
                f32x4 w0, w1;
#pragma unroll
                for (int i = 0; i < 4; ++i) {
                    w0[i] = (o0[4 * g + i] * ea + MO[(4 * g + i + idx) & 31] * eb) * inv;
                    w1[i] = (o1[4 * g + i] * ea + MO[(16 + 4 * g + i + idx) & 31] * eb) * inv;
                }
                *(f32x4*)&orow[8 * g + 4 * H]      = w0;
                *(f32x4*)&orow[32 + 8 * g + 4 * H] = w1;
            }
        }
        // next seg's prologue __syncthreads guards MO reads vs restaging
    }
}

// ---------------------------------------------------------------- launch
extern "C" void kernel_launch(void* const* d_in, const int* in_sizes, int n_in,
                              void* d_out, int out_size, void* d_ws, size_t ws_size,
                              hipStream_t stream)
{
    const float* x  = (const float*)d_in[0];
    const float* wq = (const float*)d_in[1];
    const float* bq = (const float*)d_in[2];
    const float* wk = (const float*)d_in[3];
    const float* bk = (const float*)d_in[4];
    const float* wv = (const float*)d_in[5];
    const float* bv = (const float*)d_in[6];
    const int* msk  = (const int*)d_in[7];
    float* out = (float*)d_out;

    unsigned short* xb  = (unsigned short*)d_ws;
    unsigned short* wb  = xb + (size_t)M_TOT * EMB;   // fused [3072][1024]
    unsigned short* qkv = wb + (size_t)3 * 1024 * 1024;

    cvt_kernel<<<7168, 256, 0, stream>>>(x, wq, wk, wv,
                                         xb, wb, wb + 1024 * 1024, wb + 2 * 1024 * 1024);
    qkv_gemm<<<dim3(24, 32, 1), 256, 0, stream>>>(xb, wb, bq, bk, bv, qkv);
    attn_kernel<<<dim3(32, 8, 1), 512, 0, stream>>>(
        qkv, qkv + (size_t)M_TOT * EMB, qkv + (size_t)2 * M_TOT * EMB, msk, out);
}